// Round 3
// baseline (194.213 us; speedup 1.0000x reference)
//
#include <hip/hip_runtime.h>
#include <hip/hip_bf16.h>
#include <math.h>

// WaveNet with symmetric pad (K-1)*d: the last output column of every dilated
// conv depends ONLY on the last input column (the w[...,1] tap falls in the
// zero pad: out index T+d-1, k=1 reads padded index T+d-1 >= T).
// The whole network therefore collapses to a 40-step matvec recurrence on a
// 32-vector per batch. All dtypes are float32 per the reference.
//
// Shapes: x[8,6,8192], start_w[32,6,1], filter_w/gate_w[40,32,32,2],
// res_w[40,32,32,1], skip_w[40,256,32,1], end1_w[256,256,1], end1_b[256],
// end2_w[1,256,1], end2_b[1].  Output: [8,1] -> 8 floats.

#define NLAYER 40
#define RC 32
#define DC 32
#define SC 256
#define EC 256
#define CIN 6
#define TLEN 8192

__global__ __launch_bounds__(256) void wavenet_last_col(
    const float* __restrict__ x,
    const float* __restrict__ start_w,
    const float* __restrict__ filter_w,
    const float* __restrict__ gate_w,
    const float* __restrict__ res_w,
    const float* __restrict__ skip_w,
    const float* __restrict__ end1_w,
    const float* __restrict__ end1_b,
    const float* __restrict__ end2_w,
    const float* __restrict__ end2_b,
    float* __restrict__ out)
{
    const int b = blockIdx.x;   // batch index, 0..7
    const int t = threadIdx.x;  // 0..255

    __shared__ float c[RC];     // residual channel column
    __shared__ float z[DC];     // gated output column
    __shared__ float h[SC];     // relu(skip_sum) column
    __shared__ float e[EC];     // end1 output
    __shared__ float wsum[4];

    float skip_acc = 0.0f;      // thread t owns skip channel t

    // start conv (1x1, 6->32) on the last input column
    if (t < RC) {
        float acc = 0.0f;
        #pragma unroll
        for (int j = 0; j < CIN; ++j)
            acc += start_w[t * CIN + j] * x[(b * CIN + j) * TLEN + (TLEN - 1)];
        c[t] = acc;
    }
    __syncthreads();

    for (int l = 0; l < NLAYER; ++l) {
        // gated unit: only the k=0 tap matters at the last column
        if (t < DC) {
            const float* wf = filter_w + (size_t)(l * DC + t) * RC * 2;
            const float* wg = gate_w   + (size_t)(l * DC + t) * RC * 2;
            float f = 0.0f, g = 0.0f;
            #pragma unroll
            for (int j = 0; j < RC; ++j) {
                float cj = c[j];
                f += wf[2 * j] * cj;   // kernel index 0
                g += wg[2 * j] * cj;
            }
            f = tanhf(f);
            g = 1.0f / (1.0f + expf(-g));
            z[t] = f * g;
        }
        __syncthreads();

        // skip conv 1x1 (32 -> 256): thread t accumulates its channel
        {
            const float* ws = skip_w + (size_t)(l * SC + t) * DC;
            float acc = 0.0f;
            #pragma unroll
            for (int j = 0; j < DC; ++j)
                acc += ws[j] * z[j];
            skip_acc += acc;
        }

        // res conv 1x1 (32 -> 32) + residual, into register first
        float cnew = 0.0f;
        if (t < RC) {
            const float* wr = res_w + (size_t)(l * RC + t) * DC;
            #pragma unroll
            for (int j = 0; j < DC; ++j)
                cnew += wr[j] * z[j];
            cnew += z[t];
        }
        __syncthreads();
        if (t < RC) c[t] = cnew;
        __syncthreads();
    }

    // h = relu(skip_sum) last column
    h[t] = fmaxf(skip_acc, 0.0f);
    __syncthreads();

    // end1: 256x256 matvec + bias, relu
    {
        const float* w1 = end1_w + (size_t)t * SC;
        float acc = end1_b[t];
        for (int j = 0; j < SC; ++j)
            acc += w1[j] * h[j];
        e[t] = fmaxf(acc, 0.0f);
    }
    __syncthreads();

    // end2: dot over 256 channels + bias -> scalar
    float v = end2_w[t] * e[t];
    #pragma unroll
    for (int off = 32; off > 0; off >>= 1)
        v += __shfl_down(v, off, 64);
    const int wid = t >> 6;
    if ((t & 63) == 0) wsum[wid] = v;
    __syncthreads();
    if (t == 0) {
        float s = wsum[0] + wsum[1] + wsum[2] + wsum[3] + end2_b[0];
        out[b] = s;
    }
}

extern "C" void kernel_launch(void* const* d_in, const int* in_sizes, int n_in,
                              void* d_out, int out_size, void* d_ws, size_t ws_size,
                              hipStream_t stream) {
    const float* x        = (const float*)d_in[0];
    const float* start_w  = (const float*)d_in[1];
    const float* filter_w = (const float*)d_in[2];
    const float* gate_w   = (const float*)d_in[3];
    const float* res_w    = (const float*)d_in[4];
    const float* skip_w   = (const float*)d_in[5];
    const float* end1_w   = (const float*)d_in[6];
    const float* end1_b   = (const float*)d_in[7];
    const float* end2_w   = (const float*)d_in[8];
    const float* end2_b   = (const float*)d_in[9];
    float* out = (float*)d_out;

    wavenet_last_col<<<dim3(8), dim3(256), 0, stream>>>(
        x, start_w, filter_w, gate_w, res_w, skip_w,
        end1_w, end1_b, end2_w, end2_b, out);
}

// Round 4
// 103.212 us; speedup vs baseline: 1.8817x; 1.8817x over previous
//
#include <hip/hip_runtime.h>
#include <math.h>

// WaveNet collapsed to the last time column (symmetric pad (K-1)*d makes the
// k=1 tap of every dilated conv fall in the zero pad at the final position).
// 5-stage pipeline:
//   K1  : repack filter/gate k=0 taps -> compact FG[40][2][32][32] in ws,
//         start conv -> c0[8][32], zero hsum[8][256].
//   K2  : 8 blocks x 1 wave: 40-layer recurrence from compact weights,
//         register-double-buffered prefetch, z stored per layer to ws.
//   K3a : skip matvec over (layer,batch) grid, atomicAdd into hsum.
//   K3b : relu + end1 256x256 matvec -> ebuf.
//   K3c : end2 dot -> out[8].

#define NL 40
#define TLEN 8192

// ws layout (float offsets)
#define WS_FG    0         // [40][2][32][32] = 81920
#define WS_C0    81920     // [8][32]         = 256
#define WS_Z     82176     // [40][8][32]     = 10240
#define WS_H     92416     // [8][256]        = 2048
#define WS_E     94464     // [8][256]        = 2048

// ---------------------------------------------------------------- K1: prep
__global__ __launch_bounds__(256) void k1_prep(
    const float* __restrict__ x, const float* __restrict__ start_w,
    const float* __restrict__ filter_w, const float* __restrict__ gate_w,
    float* __restrict__ ws)
{
    const int blk = blockIdx.x, t = threadIdx.x;
    if (blk < 320) {
        // dest idx e = l*2048 + fgi*1024 + ch*32 + j
        const int e  = blk * 256 + t;
        const int j  = e & 31;
        const int ch = (e >> 5) & 31;
        const int fgi = (e >> 10) & 1;
        const int l  = e >> 11;
        const float* src = fgi ? gate_w : filter_w;
        ws[WS_FG + e] = src[((l * 32 + ch) * 32 + j) * 2];  // k=0 tap
    } else {
        // block 320: start conv + zero skip accumulator
        const int b = t >> 5, ch = t & 31;
        float acc = 0.f;
        #pragma unroll
        for (int j = 0; j < 6; ++j)
            acc += start_w[ch * 6 + j] * x[(b * 6 + j) * TLEN + (TLEN - 1)];
        ws[WS_C0 + t] = acc;
        #pragma unroll
        for (int k = t; k < 2048; k += 256) ws[WS_H + k] = 0.f;
    }
}

// ------------------------------------------------------------ K2: recurrence
__device__ __forceinline__ float dot16(const float4 w[4], const float4 c[4]) {
    return w[0].x*c[0].x + w[0].y*c[0].y + w[0].z*c[0].z + w[0].w*c[0].w
         + w[1].x*c[1].x + w[1].y*c[1].y + w[1].z*c[1].z + w[1].w*c[1].w
         + w[2].x*c[2].x + w[2].y*c[2].y + w[2].z*c[2].z + w[2].w*c[2].w
         + w[3].x*c[3].x + w[3].y*c[3].y + w[3].z*c[3].z + w[3].w*c[3].w;
}

__device__ __forceinline__ float tanh_fast(float f) {
    f = fminf(fmaxf(f, -15.f), 15.f);
    float e2 = __expf(2.f * f);
    return (e2 - 1.f) / (e2 + 1.f);
}

#define LOAD_LAYER(l, F, G, R) do {                                          \
    const float4* f4 = (const float4*)(fg + (size_t)(l)*2048 + ch*32 + h*16);\
    F[0]=f4[0]; F[1]=f4[1]; F[2]=f4[2]; F[3]=f4[3];                          \
    const float4* g4 = (const float4*)(fg + (size_t)(l)*2048 + 1024          \
                                          + ch*32 + h*16);                   \
    G[0]=g4[0]; G[1]=g4[1]; G[2]=g4[2]; G[3]=g4[3];                          \
    const float4* r4 = (const float4*)(res_w + (size_t)(l)*1024              \
                                             + ch*32 + h*16);                \
    R[0]=r4[0]; R[1]=r4[1]; R[2]=r4[2]; R[3]=r4[3];                          \
} while (0)

#define COMPUTE_LAYER(l, F, G, R) do {                                       \
    float4 cc[4]; { const float4* cp = (const float4*)(csm + h*16);          \
        cc[0]=cp[0]; cc[1]=cp[1]; cc[2]=cp[2]; cc[3]=cp[3]; }                \
    float f = dot16(F, cc), g = dot16(G, cc);                                \
    f += __shfl_xor(f, 32, 64);                                              \
    g += __shfl_xor(g, 32, 64);                                              \
    float z = tanh_fast(f) * (1.f / (1.f + __expf(-g)));                     \
    if (h == 0) { zsm[ch] = z; zbuf[((l)*8 + b)*32 + ch] = z; }              \
    __builtin_amdgcn_wave_barrier();                                         \
    float4 zz[4]; { const float4* zp = (const float4*)(zsm + h*16);          \
        zz[0]=zp[0]; zz[1]=zp[1]; zz[2]=zp[2]; zz[3]=zp[3]; }                \
    float r = dot16(R, zz);                                                  \
    r += __shfl_xor(r, 32, 64);                                              \
    float cnew = r + z;                                                      \
    __builtin_amdgcn_wave_barrier();                                         \
    if (h == 0) csm[ch] = cnew;                                              \
    __builtin_amdgcn_wave_barrier();                                         \
} while (0)

__global__ __launch_bounds__(64) void k2_recur(
    const float* __restrict__ res_w, float* __restrict__ ws)
{
    const int b = blockIdx.x;           // batch
    const int lane = threadIdx.x;
    const int ch = lane & 31, h = lane >> 5;   // output channel, dot half
    const float* fg = ws + WS_FG;
    float* zbuf = ws + WS_Z;

    __shared__ float4 csm4[8];   // c[32]
    __shared__ float4 zsm4[8];   // z[32]
    float* csm = (float*)csm4;
    float* zsm = (float*)zsm4;

    if (h == 0) csm[ch] = ws[WS_C0 + b * 32 + ch];
    __builtin_amdgcn_wave_barrier();

    float4 Af[4], Ag[4], Ar[4], Bf[4], Bg[4], Br[4];
    LOAD_LAYER(0, Af, Ag, Ar);
    #pragma unroll 1
    for (int l = 0; l < NL; l += 2) {
        const int l1 = (l + 1 < NL) ? l + 1 : NL - 1;
        const int l2 = (l + 2 < NL) ? l + 2 : NL - 1;
        LOAD_LAYER(l1, Bf, Bg, Br);       // prefetch next while computing
        COMPUTE_LAYER(l, Af, Ag, Ar);
        LOAD_LAYER(l2, Af, Ag, Ar);
        COMPUTE_LAYER(l1, Bf, Bg, Br);
    }
}

// ------------------------------------------------------- K3a: skip matvec
__global__ __launch_bounds__(256) void k3a_skip(
    const float* __restrict__ skip_w, float* __restrict__ ws)
{
    const int l = blockIdx.x, b = blockIdx.y, t = threadIdx.x;
    __shared__ __align__(16) float zsm[32];
    if (t < 32) zsm[t] = ws[WS_Z + (l * 8 + b) * 32 + t];
    __syncthreads();
    const float4* w4 = (const float4*)(skip_w + (size_t)(l * 256 + t) * 32);
    const float4* z4 = (const float4*)zsm;
    float acc = 0.f;
    #pragma unroll
    for (int q = 0; q < 8; ++q) {
        float4 w = w4[q], z = z4[q];
        acc += w.x*z.x + w.y*z.y + w.z*z.z + w.w*z.w;
    }
    atomicAdd(&ws[WS_H + b * 256 + t], acc);
}

// ----------------------------------------------------------- K3b: end1
__global__ __launch_bounds__(256) void k3b_end1(
    const float* __restrict__ end1_w, const float* __restrict__ end1_b,
    float* __restrict__ ws)
{
    const int ecc = blockIdx.x, b = blockIdx.y, t = threadIdx.x;
    __shared__ __align__(16) float hsm[256];
    __shared__ float psum[64][5];
    hsm[t] = fmaxf(ws[WS_H + b * 256 + t], 0.f);   // relu(skip_sum)
    __syncthreads();
    const int oc = t & 63, p = t >> 6;
    const int ec = ecc * 64 + oc;
    const float4* w4 = (const float4*)(end1_w + (size_t)ec * 256 + p * 64);
    const float4* h4 = (const float4*)(hsm + p * 64);
    float acc = 0.f;
    #pragma unroll
    for (int q = 0; q < 16; ++q) {
        float4 w = w4[q], hh = h4[q];
        acc += w.x*hh.x + w.y*hh.y + w.z*hh.z + w.w*hh.w;
    }
    psum[oc][p] = acc;
    __syncthreads();
    if (t < 64) {
        float e = psum[t][0] + psum[t][1] + psum[t][2] + psum[t][3]
                + end1_b[ecc * 64 + t];
        ws[WS_E + b * 256 + ecc * 64 + t] = fmaxf(e, 0.f);
    }
}

// ----------------------------------------------------------- K3c: end2
__global__ __launch_bounds__(256) void k3c_out(
    const float* __restrict__ end2_w, const float* __restrict__ end2_b,
    const float* __restrict__ ws, float* __restrict__ out)
{
    const int t = threadIdx.x;
    __shared__ float wsum[4];
    for (int b = 0; b < 8; ++b) {
        float v = end2_w[t] * ws[WS_E + b * 256 + t];
        #pragma unroll
        for (int off = 32; off > 0; off >>= 1)
            v += __shfl_down(v, off, 64);
        if ((t & 63) == 0) wsum[t >> 6] = v;
        __syncthreads();
        if (t == 0)
            out[b] = wsum[0] + wsum[1] + wsum[2] + wsum[3] + end2_b[0];
        __syncthreads();
    }
}

extern "C" void kernel_launch(void* const* d_in, const int* in_sizes, int n_in,
                              void* d_out, int out_size, void* d_ws, size_t ws_size,
                              hipStream_t stream) {
    const float* x        = (const float*)d_in[0];
    const float* start_w  = (const float*)d_in[1];
    const float* filter_w = (const float*)d_in[2];
    const float* gate_w   = (const float*)d_in[3];
    const float* res_w    = (const float*)d_in[4];
    const float* skip_w   = (const float*)d_in[5];
    const float* end1_w   = (const float*)d_in[6];
    const float* end1_b   = (const float*)d_in[7];
    const float* end2_w   = (const float*)d_in[8];
    const float* end2_b   = (const float*)d_in[9];
    float* out = (float*)d_out;
    float* ws  = (float*)d_ws;

    k1_prep <<<321, 256, 0, stream>>>(x, start_w, filter_w, gate_w, ws);
    k2_recur<<<8, 64, 0, stream>>>(res_w, ws);
    k3a_skip<<<dim3(NL, 8), 256, 0, stream>>>(skip_w, ws);
    k3b_end1<<<dim3(4, 8), 256, 0, stream>>>(end1_w, end1_b, ws);
    k3c_out <<<1, 256, 0, stream>>>(end2_w, end2_b, ws, out);
}